// Round 10
// baseline (143.882 us; speedup 1.0000x reference)
//
#include <hip/hip_runtime.h>
#include <math.h>

// Round 16: continue the confirmed latency theory (R15: 2-way ILP split of
// phase A gave -17%). Now 4-way: each of the thread's 4 residues is an
// independent 3-step chain (set_delta + 2 xf_steps), all four interleaved in
// one unrolled loop -> 4 independent sincos/FMA streams.
//   P01 = P0 o P1, P23 = P2 o P3 (parallel), P = P01 o P23
//   replay prefixes: AP0=A, AP1=A o P0, AP2=A o P01, AP3=AP2 o P2
// Everything else identical to R15/R14 (9x dwordx4 loads + edge shfl,
// 6-level scan, wave0-total LDS fixup, LDS-staged contiguous store sweep).
// Spill tripwire: WRITE_SIZE must stay exactly 73728 KB.

#define LCH 512

struct Xf { float r[9]; float t[3]; };

__device__ __forceinline__ Xf xf_compose(const Xf& A, const Xf& B) {
  Xf C;
#pragma unroll
  for (int i = 0; i < 3; ++i) {
    float a0 = A.r[3*i+0], a1 = A.r[3*i+1], a2 = A.r[3*i+2];
    C.r[3*i+0] = a0*B.r[0] + a1*B.r[3] + a2*B.r[6];
    C.r[3*i+1] = a0*B.r[1] + a1*B.r[4] + a2*B.r[7];
    C.r[3*i+2] = a0*B.r[2] + a1*B.r[5] + a2*B.r[8];
    C.t[i]     = a0*B.t[0] + a1*B.t[1] + a2*B.t[2] + A.t[i];
  }
  return C;
}

// P := P o Delta(theta, len, tau), sparsity-aware (~31 FMA).
__device__ __forceinline__ void xf_step(Xf& P, float theta, float len, float tau) {
  float st, ct, sx, cx;
  __sincosf(theta, &st, &ct);
  __sincosf(tau, &sx, &cx);
  float ux = -ct, uy = cx*st, uz = sx*st;      // delta col0 (= d_local / L)
  float v0 = -st, v1 = -ct*cx, v2 = -ct*sx;    // delta col1; col2 = (0,-sx,cx)
  float c00 = P.r[0]*ux + P.r[1]*uy + P.r[2]*uz;
  float c10 = P.r[3]*ux + P.r[4]*uy + P.r[5]*uz;
  float c20 = P.r[6]*ux + P.r[7]*uy + P.r[8]*uz;
  float c01 = P.r[0]*v0 + P.r[1]*v1 + P.r[2]*v2;
  float c11 = P.r[3]*v0 + P.r[4]*v1 + P.r[5]*v2;
  float c21 = P.r[6]*v0 + P.r[7]*v1 + P.r[8]*v2;
  float c02 = P.r[2]*cx - P.r[1]*sx;
  float c12 = P.r[5]*cx - P.r[4]*sx;
  float c22 = P.r[8]*cx - P.r[7]*sx;
  P.t[0] += len*c00; P.t[1] += len*c10; P.t[2] += len*c20;
  P.r[0]=c00; P.r[1]=c01; P.r[2]=c02;
  P.r[3]=c10; P.r[4]=c11; P.r[5]=c12;
  P.r[6]=c20; P.r[7]=c21; P.r[8]=c22;
}

__device__ __forceinline__ void xf_set_delta(Xf& P, float theta, float len, float tau) {
  float st, ct, sx, cx;
  __sincosf(theta, &st, &ct);
  __sincosf(tau, &sx, &cx);
  float ux = -ct, uy = cx*st, uz = sx*st;
  P.r[0]=ux; P.r[1]=-st;    P.r[2]=0.f;
  P.r[3]=uy; P.r[4]=-ct*cx; P.r[5]=-sx;
  P.r[6]=uz; P.r[7]=-ct*sx; P.r[8]=cx;
  P.t[0]=len*ux; P.t[1]=len*uy; P.t[2]=len*uz;
}

__device__ __forceinline__ void xf_identity(Xf& A) {
  A.r[0]=1.f; A.r[1]=0.f; A.r[2]=0.f;
  A.r[3]=0.f; A.r[4]=1.f; A.r[5]=0.f;
  A.r[6]=0.f; A.r[7]=0.f; A.r[8]=1.f;
  A.t[0]=0.f; A.t[1]=0.f; A.t[2]=0.f;
}

__device__ __forceinline__ Xf xf_shfl_up(const Xf& P, int d) {
  Xf O;
#pragma unroll
  for (int i = 0; i < 9; ++i) O.r[i] = __shfl_up(P.r[i], d, 64);
#pragma unroll
  for (int i = 0; i < 3; ++i) O.t[i] = __shfl_up(P.t[i], d, 64);
  return O;
}

// one step of chain for residue m, step index k (0..2); all compile-time.
#define CSTEP(P, m, k, ax, ay, az) do { \
    float th_, ln_, ta_; \
    if      ((k) == 0) { th_ = BA[3*(m)+1]; ln_ = BL[3*(m)+2]; ta_ = PS[m]; } \
    else if ((k) == 1) { th_ = BA[3*(m)+2]; ln_ = BL[3*(m)+0]; ta_ = OM[m]; } \
    else               { th_ = BA[3*(m)+0]; ln_ = BL[3*(m)+1]; ta_ = PH[m]; } \
    if ((k) == 0) xf_set_delta(P, th_, ln_, ta_); \
    else          xf_step(P, th_, ln_, ta_); \
    ax[k] = P.t[0]; ay[k] = P.t[1]; az[k] = P.t[2]; \
  } while (0)

// replay matvec for output float f (0..35); f compile-time under unroll.
// residue rm = f/9, atom = (f%9)/3, coord = f%3.
#define REPF(f) (AP[(f)/9].r[3*((f)%3)+0]*px[(f)/9][((f)%9)/3] \
               + AP[(f)/9].r[3*((f)%3)+1]*py[(f)/9][((f)%9)/3] \
               + AP[(f)/9].r[3*((f)%3)+2]*pz[(f)/9][((f)%9)/3] \
               + AP[(f)/9].t[(f)%3])

__global__ __launch_bounds__(128) void nerf_r16_kernel(
    const float* __restrict__ g_phi, const float* __restrict__ g_psi,
    const float* __restrict__ g_omg, const float* __restrict__ g_bl,
    const float* __restrict__ g_ba, float* __restrict__ g_out)
{
  __shared__ float s_tot[12];           // wave-0 inclusive total
  __shared__ float s_out[4608];         // linear output-order staging (18 KB)

  const int t    = threadIdx.x;         // 0..127
  const int lane = t & 63;
  const int wave = t >> 6;
  const int chain = blockIdx.x;

  const float* phir = g_phi + (size_t)chain * LCH;
  const float* psir = g_psi + (size_t)chain * LCH;
  const float* omgr = g_omg + (size_t)chain * LCH;
  const float* blr  = g_bl  + (size_t)chain * (LCH*3);
  const float* bar  = g_ba  + (size_t)chain * (LCH*3);

  const int j4  = 4 * t;     // window is residues [4t-1 .. 4t+2]
  const int b12 = 12 * t;

  // ---- 9 aligned dwordx4 loads per thread ----
  float4 vps = *(const float4*)(psir + j4);
  float4 vom = *(const float4*)(omgr + j4);
  float4 vph = *(const float4*)(phir + j4);
  float4 l0  = *(const float4*)(blr + b12);
  float4 l1  = *(const float4*)(blr + b12 + 4);
  float4 l2  = *(const float4*)(blr + b12 + 8);
  float4 a0  = *(const float4*)(bar + b12);
  float4 a1  = *(const float4*)(bar + b12 + 4);
  float4 a2  = *(const float4*)(bar + b12 + 8);

  // ---- window-edge params from neighbor's tail registers ----
  float psN  = __shfl_up(vps.w, 1, 64);
  float omN  = __shfl_up(vom.w, 1, 64);
  float blN0 = __shfl_up(l2.y, 1, 64);
  float blN1 = __shfl_up(l2.z, 1, 64);
  float blN2 = __shfl_up(l2.w, 1, 64);
  float baN0 = __shfl_up(a2.y, 1, 64);
  float baN1 = __shfl_up(a2.z, 1, 64);
  float baN2 = __shfl_up(a2.w, 1, 64);
  if (lane == 0 && t != 0) {              // cross-wave edge (t == 64 only)
    psN  = psir[j4 - 1];
    omN  = omgr[j4 - 1];
    blN0 = blr[b12 - 3]; blN1 = blr[b12 - 2]; blN2 = blr[b12 - 1];
    baN0 = bar[b12 - 3]; baN1 = bar[b12 - 2]; baN2 = bar[b12 - 1];
  }
  // (t==0: edge values are junk; they feed only the discarded pre-roll chain)

  float PS[4] = { psN, vps.x, vps.y, vps.z };
  float OM[4] = { omN, vom.x, vom.y, vom.z };
  float PH[4] = { vph.x, vph.y, vph.z, vph.w };
  float BL[12] = { blN0, blN1, blN2, l0.x, l0.y, l0.z, l0.w,
                   l1.x, l1.y, l1.z, l1.w, l2.x };
  float BA[12] = { baN0, baN1, baN2, a0.x, a0.y, a0.z, a0.w,
                   a1.x, a1.y, a1.z, a1.w, a2.x };

  // ---- Phase A: FOUR independent 3-step chains, interleaved (4x ILP) ----
  Xf P0, P1, P2, P3;
  float px[4][3], py[4][3], pz[4][3];
#pragma unroll
  for (int k = 0; k < 3; ++k) {
    CSTEP(P0, 0, k, px[0], py[0], pz[0]);
    CSTEP(P1, 1, k, px[1], py[1], pz[1]);
    CSTEP(P2, 2, k, px[2], py[2], pz[2]);
    CSTEP(P3, 3, k, px[3], py[3], pz[3]);
  }
  if (t == 0) xf_identity(P0);   // discard t=0 pre-roll chain (stash junk is
                                 // overwritten by the init block in replay)

  // ---- recombine (depth-2 tree) ----
  Xf P01 = xf_compose(P0, P1);
  Xf P23 = xf_compose(P2, P3);
  Xf P   = xf_compose(P01, P23);

  // ---- intra-wave inclusive scan (non-commutative) ----
#pragma unroll
  for (int d = 1; d < 64; d <<= 1) {
    Xf O = xf_shfl_up(P, d);
    if (lane >= d) P = xf_compose(O, P);
  }

  // wave-0 total -> LDS for wave 1
  if (wave == 0 && lane == 63) {
#pragma unroll
    for (int i = 0; i < 9; ++i) s_tot[i] = P.r[i];
#pragma unroll
    for (int i = 0; i < 3; ++i) s_tot[9+i] = P.t[i];
  }
  Xf E = xf_shfl_up(P, 1);   // within-wave exclusive (junk for lane 0)
  __syncthreads();

  // ---- prefix transform A = I0 [o W0total] [o E] ----
  Xf A;
  {
    const float ax=17.047f, ay=14.099f, az=3.625f;
    const float bx_=16.967f, by_=12.784f, bz_=4.338f;
    const float cx_=15.685f, cy_=12.755f, cz_=5.133f;
    float abx=bx_-ax, aby=by_-ay, abz=bz_-az;
    float vx=cx_-bx_, vy=cy_-by_, vz=cz_-bz_;
    float vn = sqrtf(vx*vx+vy*vy+vz*vz) + 1e-8f;
    vx/=vn; vy/=vn; vz/=vn;
    float crx = aby*vz - abz*vy;
    float cry = abz*vx - abx*vz;
    float crz = abx*vy - aby*vx;
    float cn = sqrtf(crx*crx+cry*cry+crz*crz) + 1e-8f;
    float nx=crx/cn, ny=cry/cn, nz=crz/cn;
    float mx = ny*vz - nz*vy;
    float my = nz*vx - nx*vz;
    float mz = nx*vy - ny*vx;
    A.r[0]=vx; A.r[1]=mx; A.r[2]=nx;
    A.r[3]=vy; A.r[4]=my; A.r[5]=ny;
    A.r[6]=vz; A.r[7]=mz; A.r[8]=nz;
    A.t[0]=cx_; A.t[1]=cy_; A.t[2]=cz_;
  }
  if (wave == 1) {
    Xf T;
#pragma unroll
    for (int i = 0; i < 9; ++i) T.r[i] = s_tot[i];
#pragma unroll
    for (int i = 0; i < 3; ++i) T.t[i] = s_tot[9+i];
    A = xf_compose(A, T);
  }
  if (lane > 0) A = xf_compose(A, E);

  // ---- per-residue prefixes ----
  Xf AP[4];
  AP[0] = A;
  AP[1] = xf_compose(A, P0);
  AP[2] = xf_compose(A, P01);
  AP[3] = xf_compose(AP[2], P2);

  // ---- replay -> LDS staging (linear output order) ----
#pragma unroll
  for (int q = 0; q < 9; ++q) {
    float4 v;
    v.x = REPF(4*q + 0);
    v.y = REPF(4*q + 1);
    v.z = REPF(4*q + 2);
    v.w = REPF(4*q + 3);
    if (t == 0) {   // init block replaces the 3 junk pre-roll atoms (f 0..8)
      if (q == 0) { v.x=17.047f; v.y=14.099f; v.z=3.625f;  v.w=16.967f; }
      if (q == 1) { v.x=12.784f; v.y=4.338f;  v.z=15.685f; v.w=12.755f; }
      if (q == 2) { v.x=5.133f; }
    }
    *(float4*)(s_out + 36*t + 4*q) = v;
  }
  __syncthreads();

  // ---- coalesced sweep: per wave store instruction = 1024B contiguous ----
  float* orow = g_out + (size_t)chain * 4608;
#pragma unroll
  for (int p = 0; p < 9; ++p) {
    const int g = 512*p + 4*t;
    float4 v = *(const float4*)(s_out + g);
    *(float4*)(orow + g) = v;
  }
}

extern "C" void kernel_launch(void* const* d_in, const int* in_sizes, int n_in,
                              void* d_out, int out_size, void* d_ws, size_t ws_size,
                              hipStream_t stream) {
  const float* phi = (const float*)d_in[0];
  const float* psi = (const float*)d_in[1];
  const float* omg = (const float*)d_in[2];
  const float* bl  = (const float*)d_in[3];
  const float* ba  = (const float*)d_in[4];
  float* out = (float*)d_out;
  const int B = in_sizes[0] / LCH;          // 4096 chains
  hipLaunchKernelGGL(nerf_r16_kernel, dim3(B), dim3(128), 0, stream,
                     phi, psi, omg, bl, ba, out);
}